// Round 1
// baseline (357.225 us; speedup 1.0000x reference)
//
#include <hip/hip_runtime.h>

#define N_NODES 50000
#define N_EDGES 800000
#define IN_FEAT 512
#define OUT_FEAT 128

// NUMERICS CONTRACT (R3 post-mortem): the harness's np reference is matched
// bit-for-bit through the multispike quantizer ONLY when fp32 accumulation
// order is strictly sequential (k-order in GEMM, edge-order in SPMM).
// Reassociating a sum (R3's even/odd edge split) flipped a floor() boundary
// -> absmax 0.25. Do NOT split accumulator chains; get MLP from batched
// independent loads feeding ONE in-order FMA chain.

__device__ __forceinline__ float multispike(float a) {
    // floor(clamp(4x, 0, 4) + 0.5) / 4
    return floorf(fminf(fmaxf(4.0f * a, 0.0f), 4.0f) + 0.5f) * 0.25f;
}

// ---------------------------------------------------------------------------
// GEMM: C[M,128] = A[M,512] @ B[512,128], fp32 vector FMA.
// BM=64, BN=128, BK=32. 128 threads (2 waves). Thread tile 8x8.
// R5 change: register double-buffered staging (T14 async-STAGE). The grid
// gives only ~1.5 waves/SIMD, so the old {stage; sync; compute; sync} loop
// exposed the full global-load latency every chunk (VALUBusy 33%). Now the
// 12 float4 loads for chunk t+1 are ISSUED right after the top barrier of
// chunk t and CONSUMED (reg->LDS write) at the top of chunk t+1 -- the
// ~600-900 cy load latency hides under ~4096 cy of FMA issue. LDS layout,
// swizzles, barrier structure, and all accumulation chains are UNCHANGED.
// - As padded to 68: transposed-store 8-way conflict -> 4-way, rows stay
//   16B-aligned for b128 reads. A-reads conflict-free (broadcast per quad).
// - Bs XOR quad-swizzle pq = q ^ ((q>>3)&1): makes B-read 128B-stride
//   aliasing 2-way = free (m136). Same map on store and load.
// ---------------------------------------------------------------------------
__device__ __forceinline__ int bswz(int q) { return q ^ ((q >> 3) & 1); }

__global__ __launch_bounds__(128) void gemm_kernel(const float* __restrict__ A,
                                                   const float* __restrict__ B,
                                                   float* __restrict__ C, int M) {
    __shared__ float As[32][68];    // [k][m], padded
    __shared__ float Bs[32][128];   // [k][n], quad-swizzled

    const int tid = threadIdx.x;
    const int tx = tid & 15;   // n0 = tx*8
    const int ty = tid >> 4;   // m0 = ty*8  (0..7)
    const int block_m = blockIdx.x * 64;

    // read-side physical quads for this thread's two B float4s
    const int bq0 = bswz(2 * tx) * 4;
    const int bq1 = bswz(2 * tx + 1) * 4;

    float acc[8][8];
#pragma unroll
    for (int i = 0; i < 8; i++)
#pragma unroll
        for (int j = 0; j < 8; j++) acc[i][j] = 0.0f;

    // Prefetch registers: A 4x float4 (64 rows x 32 k / 128 thr),
    //                     B 8x float4 (32 rows x 128 n / 128 thr).
    float4 av[4];
    float4 bv[8];

    // ---- prologue: issue loads for chunk 0
#pragma unroll
    for (int i = 0; i < 4; i++) {
        int f = tid + i * 128;
        int r = f >> 3;
        int kq = (f & 7) << 2;
        int gm = block_m + r;
        av[i] = make_float4(0.f, 0.f, 0.f, 0.f);
        if (gm < M) av[i] = *(const float4*)(A + (size_t)gm * IN_FEAT + kq);
    }
#pragma unroll
    for (int i = 0; i < 8; i++) {
        int f = tid + i * 128;
        int r = f >> 5;             // 0..31
        int q = f & 31;             // logical quad 0..31
        bv[i] = *(const float4*)(B + (size_t)r * OUT_FEAT + q * 4);
    }

    for (int t = 0; t < 16; t++) {
        // ---- write staged chunk t (regs -> LDS); vmcnt wait lands here,
        //      ~4096 FMA-cycles after the loads were issued.
#pragma unroll
        for (int i = 0; i < 4; i++) {
            int f = tid + i * 128;
            int r = f >> 3;
            int kq = (f & 7) << 2;
            As[kq + 0][r] = av[i].x;
            As[kq + 1][r] = av[i].y;
            As[kq + 2][r] = av[i].z;
            As[kq + 3][r] = av[i].w;
        }
#pragma unroll
        for (int i = 0; i < 8; i++) {
            int f = tid + i * 128;
            int r = f >> 5;
            int q = f & 31;
            *(float4*)&Bs[r][bswz(q) * 4] = bv[i];
        }
        __syncthreads();

        // ---- issue prefetch loads for chunk t+1 (consumed next iteration)
        if (t < 15) {
            const int k0 = (t + 1) * 32;
#pragma unroll
            for (int i = 0; i < 4; i++) {
                int f = tid + i * 128;
                int r = f >> 3;
                int kq = (f & 7) << 2;
                int gm = block_m + r;
                av[i] = make_float4(0.f, 0.f, 0.f, 0.f);
                if (gm < M) av[i] = *(const float4*)(A + (size_t)gm * IN_FEAT + k0 + kq);
            }
#pragma unroll
            for (int i = 0; i < 8; i++) {
                int f = tid + i * 128;
                int r = f >> 5;
                int q = f & 31;
                bv[i] = *(const float4*)(B + (size_t)(k0 + r) * OUT_FEAT + q * 4);
            }
            // keep the loads issued HERE; don't let the scheduler sink them
            // down to their use at the top of the next iteration.
            __builtin_amdgcn_sched_barrier(0);
        }

        // ---- compute chunk t from LDS
#pragma unroll
        for (int k = 0; k < 32; k++) {
            float4 a0 = *(const float4*)&As[k][ty * 8];
            float4 a1 = *(const float4*)&As[k][ty * 8 + 4];
            float4 b0 = *(const float4*)&Bs[k][bq0];
            float4 b1 = *(const float4*)&Bs[k][bq1];
            float avv[8] = {a0.x, a0.y, a0.z, a0.w, a1.x, a1.y, a1.z, a1.w};
            float bvv[8] = {b0.x, b0.y, b0.z, b0.w, b1.x, b1.y, b1.z, b1.w};
#pragma unroll
            for (int i = 0; i < 8; i++)
#pragma unroll
                for (int j = 0; j < 8; j++)
                    acc[i][j] = fmaf(avv[i], bvv[j], acc[i][j]);
        }
        __syncthreads();
    }

#pragma unroll
    for (int i = 0; i < 8; i++) {
        int gm = block_m + ty * 8 + i;
        if (gm < M) {
            float* cp = C + (size_t)gm * OUT_FEAT + tx * 8;
            *(float4*)cp = make_float4(acc[i][0], acc[i][1], acc[i][2], acc[i][3]);
            *(float4*)(cp + 4) = make_float4(acc[i][4], acc[i][5], acc[i][6], acc[i][7]);
        }
    }
}

// ---------------------------------------------------------------------------
// row_ptr[i] = lower_bound(rows, i) over sorted rows. i in [0, N_NODES].
// ---------------------------------------------------------------------------
__global__ __launch_bounds__(256) void rowptr_kernel(const int* __restrict__ rows,
                                                     int* __restrict__ row_ptr) {
    int i = blockIdx.x * blockDim.x + threadIdx.x;
    if (i > N_NODES) return;
    int lo = 0, hi = N_EDGES;
    while (lo < hi) {
        int mid = (lo + hi) >> 1;
        if (rows[mid] < i) lo = mid + 1; else hi = mid;
    }
    row_ptr[i] = lo;
}

// ---------------------------------------------------------------------------
// SPMM + multispike: one wave per output row, lane l owns float2 l of the
// 128-float row. Unroll x8: 8 independent gathers issued per step (MLP),
// then ONE in-order FMA chain per accumulator -> summation order identical
// to the reference edge order (see NUMERICS CONTRACT above).
// ---------------------------------------------------------------------------
__global__ __launch_bounds__(256) void spmm_kernel(const float* __restrict__ x,
                                                   const int* __restrict__ cols,
                                                   const float* __restrict__ ew,
                                                   const int* __restrict__ row_ptr,
                                                   float* __restrict__ out) {
    const int wave = threadIdx.x >> 6;
    const int lane = threadIdx.x & 63;
    const int r = blockIdx.x * 4 + wave;
    if (r >= N_NODES) return;

    const int e0 = row_ptr[r];
    const int e1 = row_ptr[r + 1];
    const float2* __restrict__ x2 = (const float2*)x;

    float accx = 0.0f, accy = 0.0f;
    int e = e0;
    for (; e + 8 <= e1; e += 8) {
        int c[8];
        float w[8];
        float2 v[8];
#pragma unroll
        for (int j = 0; j < 8; j++) {
            c[j] = cols[e + j];
            w[j] = ew[e + j];
        }
#pragma unroll
        for (int j = 0; j < 8; j++) {
            v[j] = x2[(size_t)c[j] * 64 + lane];
        }
#pragma unroll
        for (int j = 0; j < 8; j++) {   // strict e-order accumulation
            accx = fmaf(w[j], v[j].x, accx);
            accy = fmaf(w[j], v[j].y, accy);
        }
    }
    for (; e < e1; e++) {
        int c = cols[e];
        float w = ew[e];
        float2 v = x2[(size_t)c * 64 + lane];
        accx = fmaf(w, v.x, accx);
        accy = fmaf(w, v.y, accy);
    }
    float2* out2 = (float2*)out;
    out2[(size_t)r * 64 + lane] = make_float2(multispike(accx), multispike(accy));
}

extern "C" void kernel_launch(void* const* d_in, const int* in_sizes, int n_in,
                              void* d_out, int out_size, void* d_ws, size_t ws_size,
                              hipStream_t stream) {
    const float* feat = (const float*)d_in[0];   // [50000, 512]
    const float* weight = (const float*)d_in[1]; // [512, 128]
    const int* rows = (const int*)d_in[2];       // [800000] sorted
    const int* cols = (const int*)d_in[3];       // [800000]
    const float* ew = (const float*)d_in[4];     // [800000]
    float* out = (float*)d_out;                  // [50000, 128]

    // Workspace layout: x [50000*128 f32] then row_ptr [50001 i32]
    float* x = (float*)d_ws;
    int* row_ptr = (int*)((char*)d_ws + (size_t)N_NODES * OUT_FEAT * sizeof(float));

    rowptr_kernel<<<(N_NODES + 256) / 256, 256, 0, stream>>>(rows, row_ptr);
    gemm_kernel<<<(N_NODES + 63) / 64, 128, 0, stream>>>(feat, weight, x, N_NODES);
    spmm_kernel<<<(N_NODES + 3) / 4, 256, 0, stream>>>(x, cols, ew, row_ptr, out);
}